// Round 4
// baseline (488.752 us; speedup 1.0000x reference)
//
#include <hip/hip_runtime.h>

#define DIN 128
#define HDIM 64

__device__ __forceinline__ unsigned short f2bf(float f) {
    unsigned u = __float_as_uint(f);
    unsigned r = (u + 0x7fffu + ((u >> 16) & 1u)) >> 16;
    return (unsigned short)r;
}
__device__ __forceinline__ float bf2f(unsigned s) {
    return __uint_as_float(s << 16);
}

// ---- histogram: cnt[dst]++ per edge ----
__global__ __launch_bounds__(256) void k_hist(const int* __restrict__ dst,
                                              int* __restrict__ cnt, int E) {
    int i = blockIdx.x * 256 + threadIdx.x;
    if (i < E) atomicAdd(&cnt[dst[i]], 1);
}

// ---- single-workgroup scan: offsets/cursor = exclusive scan(cnt); dinv = rsqrt(cnt+1) ----
__global__ __launch_bounds__(1024) void k_scan(const int* __restrict__ cnt,
                                               int* __restrict__ offsets,
                                               int* __restrict__ cursor,
                                               float* __restrict__ dinv, int n) {
    __shared__ int wsum[16];
    __shared__ int carry;
    int t = threadIdx.x, lane = t & 63, w = t >> 6;
    if (t == 0) carry = 0;
    __syncthreads();
    for (int base = 0; base < n; base += 1024) {
        int g = base + t;
        int v = (g < n) ? cnt[g] : 0;
        int s = v;
        #pragma unroll
        for (int d = 1; d < 64; d <<= 1) {
            int u = __shfl_up(s, d);
            if (lane >= d) s += u;
        }
        if (lane == 63) wsum[w] = s;
        __syncthreads();
        if (w == 0 && lane < 16) {
            int ws2 = wsum[lane];
            #pragma unroll
            for (int d = 1; d < 16; d <<= 1) {
                int u = __shfl_up(ws2, d);
                if (lane >= d) ws2 += u;
            }
            wsum[lane] = ws2;
        }
        __syncthreads();
        int excl = carry + ((w > 0) ? wsum[w - 1] : 0) + s - v;
        if (g < n) {
            offsets[g] = excl;
            cursor[g] = excl;
            dinv[g] = rsqrtf((float)v + 1.0f);
        }
        __syncthreads();
        if (t == 0) carry += wsum[15];
        __syncthreads();
    }
}

// ---- reorder: srcSorted[cursor[dst]++] = src ----
__global__ __launch_bounds__(256) void k_reorder(const int* __restrict__ src,
                                                 const int* __restrict__ dst,
                                                 int* __restrict__ cursor,
                                                 int* __restrict__ srcSorted, int E) {
    int e = blockIdx.x * 256 + threadIdx.x;
    if (e < E) {
        int d = dst[e];
        int p = atomicAdd(&cursor[d], 1);
        srcSorted[p] = src[e];
    }
}

// ---- hs[n] = (x[n] @ W1^T) * dinv[n], stored bf16 ----
__global__ __launch_bounds__(256) void k_h1(const float* __restrict__ x,
                                            const float* __restrict__ W1,
                                            const float* __restrict__ dinv,
                                            unsigned short* __restrict__ hs_bf, int n) {
    __shared__ float W1t[DIN * HDIM];
    int tid = threadIdx.x;
    for (int i = tid; i < DIN * HDIM; i += 256) {
        int h = i >> 7, k = i & 127;
        W1t[((k >> 2) * HDIM + h) * 4 + (k & 3)] = W1[i];
    }
    __syncthreads();
    const float4* W1t4 = (const float4*)W1t;
    int lane = tid & 63;
    int wave = tid >> 6;
    const int NPW = 16;
    int base = blockIdx.x * (NPW * 4) + wave * NPW;
    for (int nn = 0; nn < NPW; ++nn) {
        int node = base + nn;
        if (node >= n) break;
        const float4* xr = (const float4*)(x + (size_t)node * DIN);
        float acc = 0.f;
        #pragma unroll
        for (int k4 = 0; k4 < DIN / 4; ++k4) {
            float4 xv = xr[k4];
            float4 w = W1t4[k4 * HDIM + lane];
            acc += xv.x * w.x + xv.y * w.y + xv.z * w.z + xv.w * w.w;
        }
        hs_bf[(size_t)node * HDIM + lane] = f2bf(acc * dinv[node]);
    }
}

// ---- fused: gather-aggregate (2 rows per load) + relu + dual GEMV ----
__global__ __launch_bounds__(256) void k_gatherfinal(const int* __restrict__ offsets,
                                                     const int* __restrict__ cnt,
                                                     const int* __restrict__ srcSorted,
                                                     const unsigned short* __restrict__ hs_bf,
                                                     const float* __restrict__ dinv,
                                                     const float* __restrict__ b1,
                                                     const float* __restrict__ Wmu,
                                                     const float* __restrict__ bmu,
                                                     const float* __restrict__ Wlv,
                                                     const float* __restrict__ blv,
                                                     float* __restrict__ out, int n) {
    // W packed by j-pair: WP[p*64+o] = (W[o][2p], W[o][2p+1])
    __shared__ float2 WmuP[32 * HDIM];
    __shared__ float2 WlvP[32 * HDIM];
    int tid = threadIdx.x;
    for (int i = tid; i < 32 * HDIM; i += 256) {
        int p = i >> 6, o = i & 63;
        WmuP[i] = make_float2(Wmu[o * HDIM + 2 * p], Wmu[o * HDIM + 2 * p + 1]);
        WlvP[i] = make_float2(Wlv[o * HDIM + 2 * p], Wlv[o * HDIM + 2 * p + 1]);
    }
    __syncthreads();
    int lane = tid & 63;
    int wave = tid >> 6;
    int half = lane >> 5;      // which edge of the pair this half-wave handles
    int fpair = lane & 31;     // feature pair (2*fpair, 2*fpair+1)
    float2 bb = ((const float2*)b1)[fpair];
    float bm = bmu[lane], bl = blv[lane];
    float selfw = (half == 0) ? 1.f : 0.f;  // self-loop counted ONCE (halves combine via shfl_xor)
    const int NPW = 8;
    int base = blockIdx.x * (NPW * 4) + wave * NPW;
    for (int nn = 0; nn < NPW; ++nn) {
        int node = base + nn;
        if (node >= n) break;
        int start = offsets[node];
        int c = cnt[node];
        // self-loop term (only in half 0)
        unsigned v0 = *((const unsigned*)(hs_bf + (size_t)node * HDIM) + fpair);
        float2 a0 = make_float2(selfw * bf2f(v0 & 0xffffu), selfw * bf2f(v0 >> 16));
        float2 a1 = make_float2(0.f, 0.f);
        float2 a2 = make_float2(0.f, 0.f);
        float2 a3 = make_float2(0.f, 0.f);
        for (int i = 0; i < c; i += 64) {
            int m = c - i;
            if (m > 64) m = 64;
            int sv = (lane < m) ? srcSorted[start + i + lane] : 0;
            int npairs = (m + 1) >> 1;
            int p = 0;
            #define PAIRLOAD(ACC, Q)                                                   \
                {                                                                      \
                    int e = 2 * (Q) + half;                                            \
                    float w = 1.f;                                                     \
                    if (e >= m) { e = 0; w = 0.f; }                                    \
                    int s = __shfl(sv, e);                                             \
                    unsigned v = *((const unsigned*)(hs_bf + (size_t)s * HDIM) + fpair);\
                    ACC.x += w * bf2f(v & 0xffffu);                                    \
                    ACC.y += w * bf2f(v >> 16);                                        \
                }
            for (; p + 4 <= npairs; p += 4) {
                PAIRLOAD(a0, p)
                PAIRLOAD(a1, p + 1)
                PAIRLOAD(a2, p + 2)
                PAIRLOAD(a3, p + 3)
            }
            for (; p < npairs; ++p) PAIRLOAD(a0, p)
            #undef PAIRLOAD
        }
        float sx = a0.x + a1.x + a2.x + a3.x;
        float sy = a0.y + a1.y + a2.y + a3.y;
        sx += __shfl_xor(sx, 32);
        sy += __shfl_xor(sy, 32);
        float dn = dinv[node];
        float2 hv;
        hv.x = fmaxf(fmaf(sx, dn, bb.x), 0.f);
        hv.y = fmaxf(fmaf(sy, dn, bb.y), 0.f);
        // dual GEMV: out_o = sum_p h_{2p}*W[o][2p] + h_{2p+1}*W[o][2p+1]
        float mu = bm, lv = bl;
        #pragma unroll
        for (int p = 0; p < 32; ++p) {
            float hj0 = __shfl(hv.x, p);
            float hj1 = __shfl(hv.y, p);
            float2 wm = WmuP[p * HDIM + lane];
            float2 wl = WlvP[p * HDIM + lane];
            mu = fmaf(hj0, wm.x, fmaf(hj1, wm.y, mu));
            lv = fmaf(hj0, wl.x, fmaf(hj1, wl.y, lv));
        }
        size_t idx = (size_t)node * HDIM + lane;
        out[idx] = mu;
        out[(size_t)n * HDIM + idx] = lv;
    }
}

extern "C" void kernel_launch(void* const* d_in, const int* in_sizes, int n_in,
                              void* d_out, int out_size, void* d_ws, size_t ws_size,
                              hipStream_t stream) {
    const float* x   = (const float*)d_in[0];
    const int*   ei  = (const int*)d_in[1];
    const float* W1  = (const float*)d_in[2];
    const float* b1  = (const float*)d_in[3];
    const float* Wmu = (const float*)d_in[4];
    const float* bmu = (const float*)d_in[5];
    const float* Wlv = (const float*)d_in[6];
    const float* blv = (const float*)d_in[7];
    float* out = (float*)d_out;

    const int N = in_sizes[0] / DIN;   // 100000
    const int E = in_sizes[1] / 2;     // 1000000
    const int* src = ei;
    const int* dst = ei + E;

    auto align256 = [](size_t b) { return (b + 255) & ~(size_t)255; };
    char* ws = (char*)d_ws;
    size_t off = 0;
    float* dinv      = (float*)(ws + off); off += align256((size_t)N * 4);
    int*   cnt       = (int*)  (ws + off); off += align256((size_t)N * 4);
    int*   offsets   = (int*)  (ws + off); off += align256((size_t)N * 4);
    int*   cursor    = (int*)  (ws + off); off += align256((size_t)N * 4);
    int*   srcSorted = (int*)  (ws + off); off += align256((size_t)E * 4);
    unsigned short* hs_bf = (unsigned short*)(ws + off);
    off += align256((size_t)N * HDIM * 2);

    hipMemsetAsync(cnt, 0, (size_t)N * sizeof(int), stream);

    k_hist<<<(E + 255) / 256, 256, 0, stream>>>(dst, cnt, E);
    k_scan<<<1, 1024, 0, stream>>>(cnt, offsets, cursor, dinv, N);
    k_reorder<<<(E + 255) / 256, 256, 0, stream>>>(src, dst, cursor, srcSorted, E);
    k_h1<<<(N + 63) / 64, 256, 0, stream>>>(x, W1, dinv, hs_bf, N);
    k_gatherfinal<<<(N + 31) / 32, 256, 0, stream>>>(offsets, cnt, srcSorted, hs_bf,
                                                     dinv, b1, Wmu, bmu, Wlv, blv,
                                                     out, N);
}

// Round 5
// 296.958 us; speedup vs baseline: 1.6459x; 1.6459x over previous
//
#include <hip/hip_runtime.h>

#define DIN 128
#define HDIM 64

__device__ __forceinline__ unsigned short f2bf(float f) {
    unsigned u = __float_as_uint(f);
    unsigned r = (u + 0x7fffu + ((u >> 16) & 1u)) >> 16;
    return (unsigned short)r;
}
__device__ __forceinline__ float lo16f(unsigned v) { return __uint_as_float(v << 16); }
__device__ __forceinline__ float hi16f(unsigned v) { return __uint_as_float(v & 0xffff0000u); }

// ---- histogram: cnt[dst]++ per edge ----
__global__ __launch_bounds__(256) void k_hist(const int* __restrict__ dst,
                                              int* __restrict__ cnt, int E) {
    int i = blockIdx.x * 256 + threadIdx.x;
    if (i < E) atomicAdd(&cnt[dst[i]], 1);
}

// ---- offsets via block scan + one global atomic per block (order-free allocation) ----
__global__ __launch_bounds__(256) void k_alloc(const int* __restrict__ cnt,
                                               int* __restrict__ offsets,
                                               int* __restrict__ cursor,
                                               float* __restrict__ dinv,
                                               int* __restrict__ gcursor, int n) {
    __shared__ int wbase[4];
    int t = threadIdx.x, lane = t & 63, w = t >> 6;
    int g0 = blockIdx.x * 1024 + t * 4;
    int v[4];
    #pragma unroll
    for (int q = 0; q < 4; ++q) v[q] = (g0 + q < n) ? cnt[g0 + q] : 0;
    int tsum = v[0] + v[1] + v[2] + v[3];
    int s = tsum;
    #pragma unroll
    for (int d = 1; d < 64; d <<= 1) {
        int u = __shfl_up(s, d);
        if (lane >= d) s += u;
    }
    if (lane == 63) wbase[w] = s;
    __syncthreads();
    if (t == 0) {
        int b0 = wbase[0], b1 = wbase[1], b2 = wbase[2], b3 = wbase[3];
        int gb = atomicAdd(gcursor, b0 + b1 + b2 + b3);
        wbase[0] = gb; wbase[1] = gb + b0; wbase[2] = gb + b0 + b1; wbase[3] = gb + b0 + b1 + b2;
    }
    __syncthreads();
    int off = wbase[w] + s - tsum;
    #pragma unroll
    for (int q = 0; q < 4; ++q) {
        int g = g0 + q;
        if (g < n) {
            offsets[g] = off;
            cursor[g] = off;
            dinv[g] = rsqrtf((float)v[q] + 1.0f);
        }
        off += v[q];
    }
}

// ---- reorder: srcSorted[cursor[dst]++] = src ----
__global__ __launch_bounds__(256) void k_reorder(const int* __restrict__ src,
                                                 const int* __restrict__ dst,
                                                 int* __restrict__ cursor,
                                                 int* __restrict__ srcSorted, int E) {
    int e = blockIdx.x * 256 + threadIdx.x;
    if (e < E) {
        int d = dst[e];
        int p = atomicAdd(&cursor[d], 1);
        srcSorted[p] = src[e];
    }
}

// ---- h1 GEMM: hs[n][h] = (x[n] @ W1^T)[h] * dinv[n], stored bf16 ----
// 64x64 tile per block; LDS tiles XOR-swizzled [row][k4 ^ (row&7)] (float4 units).
// Thread (ty=t>>4, tx=t&15) computes nodes {ty+16i} x h {tx+16j} -> stride-1 row
// groups across lanes so the swizzle spreads reads over all 8 b128 slots.
__global__ __launch_bounds__(256) void k_h1(const float* __restrict__ x,
                                            const float* __restrict__ W1,
                                            const float* __restrict__ dinv,
                                            unsigned short* __restrict__ hs_bf, int n) {
    __shared__ float4 xs[64 * 32];
    __shared__ float4 ws[64 * 32];
    int t = threadIdx.x;
    int ty = t >> 4;
    int tx = t & 15;
    int nodeBase = blockIdx.x * 64;

    const float4* W14 = (const float4*)W1;  // 2048 float4
    #pragma unroll
    for (int i = 0; i < 8; ++i) {
        int f = t + i * 256;
        int r = f >> 5, c4 = f & 31;
        ws[r * 32 + (c4 ^ (r & 7))] = W14[f];
    }
    const float4* x4 = (const float4*)(x + (size_t)nodeBase * DIN);
    int limf4 = (n - nodeBase) * (DIN / 4);
    #pragma unroll
    for (int i = 0; i < 8; ++i) {
        int f = t + i * 256;
        int r = f >> 5, c4 = f & 31;
        float4 v = make_float4(0.f, 0.f, 0.f, 0.f);
        if (f < limf4) v = x4[f];
        xs[r * 32 + (c4 ^ (r & 7))] = v;
    }
    __syncthreads();

    float acc[4][4] = {};
    #pragma unroll 8
    for (int k4 = 0; k4 < 32; ++k4) {
        float4 xa[4], wb[4];
        #pragma unroll
        for (int i = 0; i < 4; ++i) {
            int r = ty + 16 * i;
            xa[i] = xs[r * 32 + (k4 ^ (r & 7))];
        }
        #pragma unroll
        for (int j = 0; j < 4; ++j) {
            int r = tx + 16 * j;
            wb[j] = ws[r * 32 + (k4 ^ (r & 7))];
        }
        #pragma unroll
        for (int i = 0; i < 4; ++i)
            #pragma unroll
            for (int j = 0; j < 4; ++j)
                acc[i][j] += xa[i].x * wb[j].x + xa[i].y * wb[j].y +
                             xa[i].z * wb[j].z + xa[i].w * wb[j].w;
    }

    #pragma unroll
    for (int i = 0; i < 4; ++i) {
        int node = nodeBase + ty + 16 * i;
        if (node < n) {
            float dn = dinv[node];
            #pragma unroll
            for (int j = 0; j < 4; ++j)
                hs_bf[(size_t)node * HDIM + tx + 16 * j] = f2bf(acc[i][j] * dn);
        }
    }
}

// ---- fused: gather-aggregate (2 rows per load) + relu + dual GEMV (bf16 weights) ----
__global__ __launch_bounds__(256) void k_gatherfinal(const int* __restrict__ offsets,
                                                     const int* __restrict__ cnt,
                                                     const int* __restrict__ srcSorted,
                                                     const unsigned short* __restrict__ hs_bf,
                                                     const float* __restrict__ dinv,
                                                     const float* __restrict__ b1,
                                                     const float* __restrict__ Wmu,
                                                     const float* __restrict__ bmu,
                                                     const float* __restrict__ Wlv,
                                                     const float* __restrict__ blv,
                                                     float* __restrict__ out, int n) {
    // packed bf16 j-pairs: WB[p*64+o] = bf16(W[o][2p]) | bf16(W[o][2p+1])<<16
    __shared__ unsigned WmuB[32 * HDIM];
    __shared__ unsigned WlvB[32 * HDIM];
    int tid = threadIdx.x;
    for (int i = tid; i < 32 * HDIM; i += 256) {
        int p = i >> 6, o = i & 63;
        WmuB[i] = (unsigned)f2bf(Wmu[o * HDIM + 2 * p]) |
                  ((unsigned)f2bf(Wmu[o * HDIM + 2 * p + 1]) << 16);
        WlvB[i] = (unsigned)f2bf(Wlv[o * HDIM + 2 * p]) |
                  ((unsigned)f2bf(Wlv[o * HDIM + 2 * p + 1]) << 16);
    }
    __syncthreads();
    int lane = tid & 63;
    int wave = tid >> 6;
    int half = lane >> 5;
    int fpair = lane & 31;
    float2 bb = ((const float2*)b1)[fpair];
    float bm = bmu[lane], bl = blv[lane];
    float selfw = (half == 0) ? 1.f : 0.f;  // self-loop counted once
    const int NPW = 4;
    int base = blockIdx.x * (NPW * 4) + wave * NPW;
    for (int nn = 0; nn < NPW; ++nn) {
        int node = base + nn;
        if (node >= n) break;
        int start = offsets[node];
        int c = cnt[node];
        unsigned v0 = *((const unsigned*)(hs_bf + (size_t)node * HDIM) + fpair);
        float2 a0 = make_float2(selfw * lo16f(v0), selfw * hi16f(v0));
        float2 a1 = make_float2(0.f, 0.f);
        float2 a2 = make_float2(0.f, 0.f);
        float2 a3 = make_float2(0.f, 0.f);
        for (int i = 0; i < c; i += 64) {
            int m = c - i;
            if (m > 64) m = 64;
            int sv = (lane < m) ? srcSorted[start + i + lane] : 0;
            int npairs = (m + 1) >> 1;
            int p = 0;
            #define PAIRLOAD(ACC, Q)                                                    \
                {                                                                       \
                    int e = 2 * (Q) + half;                                             \
                    float w = 1.f;                                                      \
                    if (e >= m) { e = 0; w = 0.f; }                                     \
                    int s = __shfl(sv, e);                                              \
                    unsigned v = *((const unsigned*)(hs_bf + (size_t)s * HDIM) + fpair);\
                    ACC.x += w * lo16f(v);                                              \
                    ACC.y += w * hi16f(v);                                              \
                }
            for (; p + 4 <= npairs; p += 4) {
                PAIRLOAD(a0, p)
                PAIRLOAD(a1, p + 1)
                PAIRLOAD(a2, p + 2)
                PAIRLOAD(a3, p + 3)
            }
            for (; p < npairs; ++p) PAIRLOAD(a0, p)
            #undef PAIRLOAD
        }
        float sx = a0.x + a1.x + a2.x + a3.x;
        float sy = a0.y + a1.y + a2.y + a3.y;
        sx += __shfl_xor(sx, 32);
        sy += __shfl_xor(sy, 32);
        float dn = dinv[node];
        float hx = fmaxf(fmaf(sx, dn, bb.x), 0.f);
        float hy = fmaxf(fmaf(sy, dn, bb.y), 0.f);
        float mu = bm, lv = bl;
        #pragma unroll
        for (int p = 0; p < 32; ++p) {
            float hj0 = __shfl(hx, p);
            float hj1 = __shfl(hy, p);
            unsigned wm = WmuB[p * HDIM + lane];
            unsigned wl = WlvB[p * HDIM + lane];
            mu = fmaf(hj0, lo16f(wm), fmaf(hj1, hi16f(wm), mu));
            lv = fmaf(hj0, lo16f(wl), fmaf(hj1, hi16f(wl), lv));
        }
        size_t idx = (size_t)node * HDIM + lane;
        out[idx] = mu;
        out[(size_t)n * HDIM + idx] = lv;
    }
}

extern "C" void kernel_launch(void* const* d_in, const int* in_sizes, int n_in,
                              void* d_out, int out_size, void* d_ws, size_t ws_size,
                              hipStream_t stream) {
    const float* x   = (const float*)d_in[0];
    const int*   ei  = (const int*)d_in[1];
    const float* W1  = (const float*)d_in[2];
    const float* b1  = (const float*)d_in[3];
    const float* Wmu = (const float*)d_in[4];
    const float* bmu = (const float*)d_in[5];
    const float* Wlv = (const float*)d_in[6];
    const float* blv = (const float*)d_in[7];
    float* out = (float*)d_out;

    const int N = in_sizes[0] / DIN;   // 100000
    const int E = in_sizes[1] / 2;     // 1000000
    const int* src = ei;
    const int* dst = ei + E;

    auto align256 = [](size_t b) { return (b + 255) & ~(size_t)255; };
    char* ws = (char*)d_ws;
    size_t off = 0;
    float* dinv      = (float*)(ws + off); off += align256((size_t)N * 4);
    int*   gcursor   = (int*)  (ws + off); off += 256;
    int*   cnt       = (int*)  (ws + off); off += align256((size_t)N * 4);
    int*   offsets   = (int*)  (ws + off); off += align256((size_t)N * 4);
    int*   cursor    = (int*)  (ws + off); off += align256((size_t)N * 4);
    int*   srcSorted = (int*)  (ws + off); off += align256((size_t)E * 4);
    unsigned short* hs_bf = (unsigned short*)(ws + off);
    off += align256((size_t)N * HDIM * 2);

    // zero gcursor + cnt in one shot (adjacent)
    hipMemsetAsync(gcursor, 0, 256 + align256((size_t)N * 4), stream);

    k_hist<<<(E + 255) / 256, 256, 0, stream>>>(dst, cnt, E);
    k_alloc<<<(N + 1023) / 1024, 256, 0, stream>>>(cnt, offsets, cursor, dinv, gcursor, N);
    k_reorder<<<(E + 255) / 256, 256, 0, stream>>>(src, dst, cursor, srcSorted, E);
    k_h1<<<(N + 63) / 64, 256, 0, stream>>>(x, W1, dinv, hs_bf, N);
    k_gatherfinal<<<(N + 15) / 16, 256, 0, stream>>>(offsets, cnt, srcSorted, hs_bf,
                                                     dinv, b1, Wmu, bmu, Wlv, blv,
                                                     out, N);
}

// Round 6
// 252.289 us; speedup vs baseline: 1.9373x; 1.1771x over previous
//
#include <hip/hip_runtime.h>

#define DIN 128
#define HDIM 64

__device__ __forceinline__ unsigned short f2bf(float f) {
    unsigned u = __float_as_uint(f);
    unsigned r = (u + 0x7fffu + ((u >> 16) & 1u)) >> 16;
    return (unsigned short)r;
}
__device__ __forceinline__ float lo16f(unsigned v) { return __uint_as_float(v << 16); }
__device__ __forceinline__ float hi16f(unsigned v) { return __uint_as_float(v & 0xffff0000u); }

// ---- histogram: cnt[dst]++ per edge ----
__global__ __launch_bounds__(256) void k_hist(const int* __restrict__ dst,
                                              int* __restrict__ cnt, int E) {
    int i = blockIdx.x * 256 + threadIdx.x;
    if (i < E) atomicAdd(&cnt[dst[i]], 1);
}

// ---- offsets via block scan + one global atomic per block; allocates c+1 slots
//      per node and plants the self-loop entry; dinv = rsqrt(c+1) ----
__global__ __launch_bounds__(256) void k_alloc(const int* __restrict__ cnt,
                                               int* __restrict__ offsets,
                                               int* __restrict__ cursor,
                                               float* __restrict__ dinv,
                                               int* __restrict__ srcSorted,
                                               int* __restrict__ gcursor, int n) {
    __shared__ int wbase[4];
    int t = threadIdx.x, lane = t & 63, w = t >> 6;
    int g0 = blockIdx.x * 1024 + t * 4;
    int v[4];
    #pragma unroll
    for (int q = 0; q < 4; ++q) v[q] = (g0 + q < n) ? (cnt[g0 + q] + 1) : 0;
    int tsum = v[0] + v[1] + v[2] + v[3];
    int s = tsum;
    #pragma unroll
    for (int d = 1; d < 64; d <<= 1) {
        int u = __shfl_up(s, d);
        if (lane >= d) s += u;
    }
    if (lane == 63) wbase[w] = s;
    __syncthreads();
    if (t == 0) {
        int b0 = wbase[0], b1 = wbase[1], b2 = wbase[2], b3 = wbase[3];
        int gb = atomicAdd(gcursor, b0 + b1 + b2 + b3);
        wbase[0] = gb; wbase[1] = gb + b0; wbase[2] = gb + b0 + b1; wbase[3] = gb + b0 + b1 + b2;
    }
    __syncthreads();
    int off = wbase[w] + s - tsum;
    #pragma unroll
    for (int q = 0; q < 4; ++q) {
        int g = g0 + q;
        if (g < n) {
            offsets[g] = off;
            srcSorted[off] = g;       // self-loop entry
            cursor[g] = off + 1;      // edges fill after the self entry
            dinv[g] = rsqrtf((float)v[q]);
        }
        off += v[q];
    }
}

// ---- reorder: srcSorted[cursor[dst]++] = src ----
__global__ __launch_bounds__(256) void k_reorder(const int* __restrict__ src,
                                                 const int* __restrict__ dst,
                                                 int* __restrict__ cursor,
                                                 int* __restrict__ srcSorted, int E) {
    int e = blockIdx.x * 256 + threadIdx.x;
    if (e < E) {
        int d = dst[e];
        int p = atomicAdd(&cursor[d], 1);
        srcSorted[p] = src[e];
    }
}

// ---- h1 GEMM: hs[n][h] = (x[n] @ W1^T)[h] * dinv[n], stored bf16 ----
__global__ __launch_bounds__(256) void k_h1(const float* __restrict__ x,
                                            const float* __restrict__ W1,
                                            const float* __restrict__ dinv,
                                            unsigned short* __restrict__ hs_bf, int n) {
    __shared__ float4 xs[64 * 32];
    __shared__ float4 ws[64 * 32];
    int t = threadIdx.x;
    int ty = t >> 4;
    int tx = t & 15;
    int nodeBase = blockIdx.x * 64;

    const float4* W14 = (const float4*)W1;
    #pragma unroll
    for (int i = 0; i < 8; ++i) {
        int f = t + i * 256;
        int r = f >> 5, c4 = f & 31;
        ws[r * 32 + (c4 ^ (r & 7))] = W14[f];
    }
    const float4* x4 = (const float4*)(x + (size_t)nodeBase * DIN);
    int limf4 = (n - nodeBase) * (DIN / 4);
    #pragma unroll
    for (int i = 0; i < 8; ++i) {
        int f = t + i * 256;
        int r = f >> 5, c4 = f & 31;
        float4 v = make_float4(0.f, 0.f, 0.f, 0.f);
        if (f < limf4) v = x4[f];
        xs[r * 32 + (c4 ^ (r & 7))] = v;
    }
    __syncthreads();

    float acc[4][4] = {};
    #pragma unroll 8
    for (int k4 = 0; k4 < 32; ++k4) {
        float4 xa[4], wb[4];
        #pragma unroll
        for (int i = 0; i < 4; ++i) {
            int r = ty + 16 * i;
            xa[i] = xs[r * 32 + (k4 ^ (r & 7))];
        }
        #pragma unroll
        for (int j = 0; j < 4; ++j) {
            int r = tx + 16 * j;
            wb[j] = ws[r * 32 + (k4 ^ (r & 7))];
        }
        #pragma unroll
        for (int i = 0; i < 4; ++i)
            #pragma unroll
            for (int j = 0; j < 4; ++j)
                acc[i][j] += xa[i].x * wb[j].x + xa[i].y * wb[j].y +
                             xa[i].z * wb[j].z + xa[i].w * wb[j].w;
    }

    #pragma unroll
    for (int i = 0; i < 4; ++i) {
        int node = nodeBase + ty + 16 * i;
        if (node < n) {
            float dn = dinv[node];
            #pragma unroll
            for (int j = 0; j < 4; ++j)
                hs_bf[(size_t)node * HDIM + tx + 16 * j] = f2bf(acc[i][j] * dn);
        }
    }
}

// ---- gather-aggregate + bias + relu -> h fp32 ----
// One node per wave; 4 edges per load instr (16 lanes x 8B cover one 128B row).
__global__ __launch_bounds__(256) void k_gather(const int* __restrict__ offsets,
                                                const int* __restrict__ cnt,
                                                const int* __restrict__ srcSorted,
                                                const unsigned short* __restrict__ hs_bf,
                                                const float* __restrict__ dinv,
                                                const float* __restrict__ b1,
                                                float* __restrict__ h, int n) {
    int tid = threadIdx.x;
    int lane = tid & 63, wave = tid >> 6;
    int grp = lane >> 4;      // edge slot within quad
    int w = lane & 15;        // feature quad: feats 4w..4w+3
    float4 bb = ((const float4*)b1)[w];
    const int NPW = 8;
    int base = blockIdx.x * (4 * NPW) + wave * NPW;
    for (int nn = 0; nn < NPW; ++nn) {
        int node = base + nn;
        if (node >= n) break;
        int start = offsets[node];
        int c = cnt[node] + 1;  // incl. self entry
        float a0 = 0.f, a1 = 0.f, a2 = 0.f, a3 = 0.f;
        for (int i = 0; i < c; i += 64) {
            int m = c - i;
            if (m > 64) m = 64;
            int sv = (lane < m) ? srcSorted[start + i + lane] : 0;
            int nfull = m >> 2;
            for (int q = 0; q < nfull; ++q) {
                int s = __shfl(sv, 4 * q + grp);
                uint2 v = *(const uint2*)(hs_bf + ((size_t)s << 6) + 4 * w);
                a0 += lo16f(v.x); a1 += hi16f(v.x);
                a2 += lo16f(v.y); a3 += hi16f(v.y);
            }
            int r = m & 3;
            if (r) {
                int e = 4 * nfull + grp;
                float wt = (grp < r) ? 1.f : 0.f;
                int s = __shfl(sv, (e < m) ? e : 0);
                uint2 v = *(const uint2*)(hs_bf + ((size_t)s << 6) + 4 * w);
                a0 += wt * lo16f(v.x); a1 += wt * hi16f(v.x);
                a2 += wt * lo16f(v.y); a3 += wt * hi16f(v.y);
            }
        }
        a0 += __shfl_xor(a0, 16); a0 += __shfl_xor(a0, 32);
        a1 += __shfl_xor(a1, 16); a1 += __shfl_xor(a1, 32);
        a2 += __shfl_xor(a2, 16); a2 += __shfl_xor(a2, 32);
        a3 += __shfl_xor(a3, 16); a3 += __shfl_xor(a3, 32);
        float dn = dinv[node];
        float h0 = fmaxf(fmaf(a0, dn, bb.x), 0.f);
        float h1v = fmaxf(fmaf(a1, dn, bb.y), 0.f);
        float h2 = fmaxf(fmaf(a2, dn, bb.z), 0.f);
        float h3 = fmaxf(fmaf(a3, dn, bb.w), 0.f);
        if (grp == 0)
            *(float4*)(h + (size_t)node * HDIM + 4 * w) = make_float4(h0, h1v, h2, h3);
    }
}

// ---- out GEMM: out = [h @ Wmu^T + bmu ; h @ Wlv^T + blv], tiled like k_h1 ----
__global__ __launch_bounds__(256) void k_out(const float* __restrict__ h,
                                             const float* __restrict__ Wmu,
                                             const float* __restrict__ bmu,
                                             const float* __restrict__ Wlv,
                                             const float* __restrict__ blv,
                                             float* __restrict__ out, int n) {
    __shared__ float4 xs[64 * 16];   // h tile: 64 nodes x 64 feats
    __shared__ float4 ws[128 * 16];  // [Wmu;Wlv]: 128 outs x 64 feats
    int t = threadIdx.x;
    int ty = t >> 4;
    int tx = t & 15;
    int nodeBase = blockIdx.x * 64;

    const float4* Wm4 = (const float4*)Wmu;  // 1024 float4
    const float4* Wl4 = (const float4*)Wlv;
    #pragma unroll
    for (int i = 0; i < 4; ++i) {
        int f = t + i * 256;
        int r = f >> 4, c4 = f & 15;
        ws[r * 16 + (c4 ^ (r & 15))] = Wm4[f];
        int r2 = r + 64;
        ws[r2 * 16 + (c4 ^ (r2 & 15))] = Wl4[f];
    }
    const float4* h4 = (const float4*)(h + (size_t)nodeBase * HDIM);
    int limf4 = (n - nodeBase) * (HDIM / 4);
    #pragma unroll
    for (int i = 0; i < 4; ++i) {
        int f = t + i * 256;
        int r = f >> 4, c4 = f & 15;
        float4 v = make_float4(0.f, 0.f, 0.f, 0.f);
        if (f < limf4) v = h4[f];
        xs[r * 16 + (c4 ^ (r & 15))] = v;
    }
    float bias[8];
    #pragma unroll
    for (int j = 0; j < 8; ++j) {
        int o = tx + 16 * j;
        bias[j] = (o < 64) ? bmu[o] : blv[o - 64];
    }
    __syncthreads();

    float acc[4][8] = {};
    #pragma unroll 4
    for (int k4 = 0; k4 < 16; ++k4) {
        float4 xa[4], wb[8];
        #pragma unroll
        for (int i = 0; i < 4; ++i) {
            int r = ty + 16 * i;
            xa[i] = xs[r * 16 + (k4 ^ (r & 15))];
        }
        #pragma unroll
        for (int j = 0; j < 8; ++j) {
            int r = tx + 16 * j;
            wb[j] = ws[r * 16 + (k4 ^ (r & 15))];
        }
        #pragma unroll
        for (int i = 0; i < 4; ++i)
            #pragma unroll
            for (int j = 0; j < 8; ++j)
                acc[i][j] += xa[i].x * wb[j].x + xa[i].y * wb[j].y +
                             xa[i].z * wb[j].z + xa[i].w * wb[j].w;
    }

    #pragma unroll
    for (int i = 0; i < 4; ++i) {
        int node = nodeBase + ty + 16 * i;
        if (node < n) {
            #pragma unroll
            for (int j = 0; j < 8; ++j) {
                int o = tx + 16 * j;
                float val = acc[i][j] + bias[j];
                if (o < 64)
                    out[(size_t)node * HDIM + o] = val;
                else
                    out[(size_t)n * HDIM + (size_t)node * HDIM + (o - 64)] = val;
            }
        }
    }
}

extern "C" void kernel_launch(void* const* d_in, const int* in_sizes, int n_in,
                              void* d_out, int out_size, void* d_ws, size_t ws_size,
                              hipStream_t stream) {
    const float* x   = (const float*)d_in[0];
    const int*   ei  = (const int*)d_in[1];
    const float* W1  = (const float*)d_in[2];
    const float* b1  = (const float*)d_in[3];
    const float* Wmu = (const float*)d_in[4];
    const float* bmu = (const float*)d_in[5];
    const float* Wlv = (const float*)d_in[6];
    const float* blv = (const float*)d_in[7];
    float* out = (float*)d_out;

    const int N = in_sizes[0] / DIN;   // 100000
    const int E = in_sizes[1] / 2;     // 1000000
    const int* src = ei;
    const int* dst = ei + E;

    auto align256 = [](size_t b) { return (b + 255) & ~(size_t)255; };
    char* ws = (char*)d_ws;
    size_t off = 0;
    float* dinv      = (float*)(ws + off); off += align256((size_t)N * 4);
    int*   gcursor   = (int*)  (ws + off); off += 256;
    int*   cnt       = (int*)  (ws + off); off += align256((size_t)N * 4);
    int*   offsets   = (int*)  (ws + off); off += align256((size_t)N * 4);
    int*   cursor    = (int*)  (ws + off); off += align256((size_t)N * 4);
    int*   srcSorted = (int*)  (ws + off); off += align256(((size_t)E + N) * 4);
    unsigned short* hs_bf = (unsigned short*)(ws + off);
    off += align256((size_t)N * HDIM * 2);
    float* h = (float*)(ws + off); off += align256((size_t)N * HDIM * 4);

    // zero gcursor + cnt in one shot (adjacent)
    hipMemsetAsync(gcursor, 0, 256 + align256((size_t)N * 4), stream);

    k_hist<<<(E + 255) / 256, 256, 0, stream>>>(dst, cnt, E);
    k_alloc<<<(N + 1023) / 1024, 256, 0, stream>>>(cnt, offsets, cursor, dinv,
                                                   srcSorted, gcursor, N);
    k_reorder<<<(E + 255) / 256, 256, 0, stream>>>(src, dst, cursor, srcSorted, E);
    k_h1<<<(N + 63) / 64, 256, 0, stream>>>(x, W1, dinv, hs_bf, N);
    k_gather<<<(N + 31) / 32, 256, 0, stream>>>(offsets, cnt, srcSorted, hs_bf,
                                                dinv, b1, h, N);
    k_out<<<(N + 63) / 64, 256, 0, stream>>>(h, Wmu, bmu, Wlv, blv, out, N);
}

// Round 7
// 194.292 us; speedup vs baseline: 2.5156x; 1.2985x over previous
//
#include <hip/hip_runtime.h>

#define DIN 128
#define HDIM 64
#define SLAB 32
#define OVF_CAP 65536

__device__ __forceinline__ unsigned short f2bf(float f) {
    unsigned u = __float_as_uint(f);
    unsigned r = (u + 0x7fffu + ((u >> 16) & 1u)) >> 16;
    return (unsigned short)r;
}
__device__ __forceinline__ float lo16f(unsigned v) { return __uint_as_float(v << 16); }
__device__ __forceinline__ float hi16f(unsigned v) { return __uint_as_float(v & 0xffff0000u); }

// ---- single-pass CSR: p = cursor[d]++; slab[d*32+p] = src (overflow -> side list) ----
__global__ __launch_bounds__(256) void k_scatter(const int* __restrict__ src,
                                                 const int* __restrict__ dst,
                                                 int* __restrict__ cursor,
                                                 int* __restrict__ slab,
                                                 int* __restrict__ ovf,
                                                 int* __restrict__ govf, int E) {
    int e = blockIdx.x * 256 + threadIdx.x;
    if (e < E) {
        int d = dst[e], s = src[e];
        int p = atomicAdd(&cursor[d], 1);
        if (p < SLAB) {
            slab[(size_t)d * SLAB + p] = s;
        } else {
            int o = atomicAdd(govf, 1);
            if (o < OVF_CAP) { ovf[2 * o] = d; ovf[2 * o + 1] = s; }
        }
    }
}

// ---- h1 GEMM: hs[n][h] = (x[n] @ W1^T)[h] * rsqrt(deg+1), stored bf16 ----
__global__ __launch_bounds__(256) void k_h1(const float* __restrict__ x,
                                            const float* __restrict__ W1,
                                            const int* __restrict__ cursor,
                                            unsigned short* __restrict__ hs_bf, int n) {
    __shared__ float4 xs[64 * 32];
    __shared__ float4 ws[64 * 32];
    int t = threadIdx.x;
    int ty = t >> 4;
    int tx = t & 15;
    int nodeBase = blockIdx.x * 64;

    const float4* W14 = (const float4*)W1;
    #pragma unroll
    for (int i = 0; i < 8; ++i) {
        int f = t + i * 256;
        int r = f >> 5, c4 = f & 31;
        ws[r * 32 + (c4 ^ (r & 7))] = W14[f];
    }
    const float4* x4 = (const float4*)(x + (size_t)nodeBase * DIN);
    int limf4 = (n - nodeBase) * (DIN / 4);
    #pragma unroll
    for (int i = 0; i < 8; ++i) {
        int f = t + i * 256;
        int r = f >> 5, c4 = f & 31;
        float4 v = make_float4(0.f, 0.f, 0.f, 0.f);
        if (f < limf4) v = x4[f];
        xs[r * 32 + (c4 ^ (r & 7))] = v;
    }
    __syncthreads();

    float acc[4][4] = {};
    #pragma unroll 8
    for (int k4 = 0; k4 < 32; ++k4) {
        float4 xa[4], wb[4];
        #pragma unroll
        for (int i = 0; i < 4; ++i) {
            int r = ty + 16 * i;
            xa[i] = xs[r * 32 + (k4 ^ (r & 7))];
        }
        #pragma unroll
        for (int j = 0; j < 4; ++j) {
            int r = tx + 16 * j;
            wb[j] = ws[r * 32 + (k4 ^ (r & 7))];
        }
        #pragma unroll
        for (int i = 0; i < 4; ++i)
            #pragma unroll
            for (int j = 0; j < 4; ++j)
                acc[i][j] += xa[i].x * wb[j].x + xa[i].y * wb[j].y +
                             xa[i].z * wb[j].z + xa[i].w * wb[j].w;
    }

    #pragma unroll
    for (int i = 0; i < 4; ++i) {
        int node = nodeBase + ty + 16 * i;
        if (node < n) {
            float dn = rsqrtf((float)cursor[node] + 1.0f);
            #pragma unroll
            for (int j = 0; j < 4; ++j)
                hs_bf[(size_t)node * HDIM + tx + 16 * j] = f2bf(acc[i][j] * dn);
        }
    }
}

// ---- gather: h[node] = hs[node] + sum_slab hs[src]  (raw, pre-activation) ----
// One node per wave: 16 feat-lanes (uint2 = 4 feats) x 4 edge-groups.
__global__ __launch_bounds__(256) void k_gather(const int* __restrict__ cursor,
                                                const int* __restrict__ slab,
                                                const unsigned short* __restrict__ hs_bf,
                                                float* __restrict__ h, int n) {
    int tid = threadIdx.x;
    int lane = tid & 63, wave = tid >> 6;
    int grp = lane >> 4;
    int w = lane & 15;
    const int NPW = 8;
    int base = blockIdx.x * (4 * NPW) + wave * NPW;
    for (int nn = 0; nn < NPW; ++nn) {
        int node = base + nn;
        if (node >= n) break;
        int c = cursor[node];
        int cs = (c < SLAB) ? c : SLAB;
        int sv = (lane < cs) ? slab[(size_t)node * SLAB + lane] : 0;
        // self-loop term, counted once (grp 0 only)
        uint2 v0 = *(const uint2*)(hs_bf + ((size_t)node << 6) + 4 * w);
        float sw = (grp == 0) ? 1.f : 0.f;
        float a0 = sw * lo16f(v0.x), a1 = sw * hi16f(v0.x);
        float a2 = sw * lo16f(v0.y), a3 = sw * hi16f(v0.y);
        int nfull = cs >> 2;
        for (int q = 0; q < nfull; ++q) {
            int s = __shfl(sv, 4 * q + grp);
            uint2 v = *(const uint2*)(hs_bf + ((size_t)s << 6) + 4 * w);
            a0 += lo16f(v.x); a1 += hi16f(v.x);
            a2 += lo16f(v.y); a3 += hi16f(v.y);
        }
        int r = cs & 3;
        if (r) {
            int e = 4 * nfull + grp;
            float wt = (grp < r) ? 1.f : 0.f;
            int s = __shfl(sv, (e < SLAB) ? e : 0);
            uint2 v = *(const uint2*)(hs_bf + ((size_t)s << 6) + 4 * w);
            a0 += wt * lo16f(v.x); a1 += wt * hi16f(v.x);
            a2 += wt * lo16f(v.y); a3 += wt * hi16f(v.y);
        }
        a0 += __shfl_xor(a0, 16); a0 += __shfl_xor(a0, 32);
        a1 += __shfl_xor(a1, 16); a1 += __shfl_xor(a1, 32);
        a2 += __shfl_xor(a2, 16); a2 += __shfl_xor(a2, 32);
        a3 += __shfl_xor(a3, 16); a3 += __shfl_xor(a3, 32);
        if (lane < 16)
            *(float4*)(h + ((size_t)node << 6) + 4 * w) = make_float4(a0, a1, a2, a3);
    }
}

// ---- rare overflow edges (deg > 32): atomic add into raw h ----
__global__ __launch_bounds__(256) void k_overflow(const int* __restrict__ govf,
                                                  const int* __restrict__ ovf,
                                                  const unsigned short* __restrict__ hs_bf,
                                                  float* __restrict__ h) {
    int novf = govf[0];
    if (novf > OVF_CAP) novf = OVF_CAP;
    int wid = (blockIdx.x * 256 + threadIdx.x) >> 6;
    int lane = threadIdx.x & 63;
    int nw = (gridDim.x * 256) >> 6;
    for (int i = wid; i < novf; i += nw) {
        int d = ovf[2 * i], s = ovf[2 * i + 1];
        atomicAdd(&h[(size_t)d * HDIM + lane],
                  lo16f((unsigned)hs_bf[(size_t)s * HDIM + lane]));
    }
}

// ---- out GEMM with fused activation on load:
//      hact = relu(h*rsqrt(deg+1) + b1); out = [hact@Wmu^T+bmu ; hact@Wlv^T+blv] ----
__global__ __launch_bounds__(256) void k_out(const float* __restrict__ h,
                                             const int* __restrict__ cursor,
                                             const float* __restrict__ b1,
                                             const float* __restrict__ Wmu,
                                             const float* __restrict__ bmu,
                                             const float* __restrict__ Wlv,
                                             const float* __restrict__ blv,
                                             float* __restrict__ out, int n) {
    __shared__ float4 xs[64 * 16];   // activated h tile: 64 nodes x 64 feats
    __shared__ float4 ws[128 * 16];  // [Wmu;Wlv]: 128 outs x 64 feats
    int t = threadIdx.x;
    int ty = t >> 4;
    int tx = t & 15;
    int nodeBase = blockIdx.x * 64;

    const float4* Wm4 = (const float4*)Wmu;
    const float4* Wl4 = (const float4*)Wlv;
    #pragma unroll
    for (int i = 0; i < 4; ++i) {
        int f = t + i * 256;
        int r = f >> 4, c4 = f & 15;
        ws[r * 16 + (c4 ^ (r & 15))] = Wm4[f];
        int r2 = r + 64;
        ws[r2 * 16 + (c4 ^ (r2 & 15))] = Wl4[f];
    }
    const float4* h4 = (const float4*)(h + (size_t)nodeBase * HDIM);
    int limf4 = (n - nodeBase) * (HDIM / 4);
    #pragma unroll
    for (int i = 0; i < 4; ++i) {
        int f = t + i * 256;
        int r = f >> 4, c4 = f & 15;
        float4 v = make_float4(0.f, 0.f, 0.f, 0.f);
        if (f < limf4) {
            v = h4[f];
            float dn = rsqrtf((float)cursor[nodeBase + r] + 1.0f);
            float4 bb = ((const float4*)b1)[c4];
            v.x = fmaxf(fmaf(v.x, dn, bb.x), 0.f);
            v.y = fmaxf(fmaf(v.y, dn, bb.y), 0.f);
            v.z = fmaxf(fmaf(v.z, dn, bb.z), 0.f);
            v.w = fmaxf(fmaf(v.w, dn, bb.w), 0.f);
        }
        xs[r * 16 + (c4 ^ (r & 15))] = v;
    }
    float bias[8];
    #pragma unroll
    for (int j = 0; j < 8; ++j) {
        int o = tx + 16 * j;
        bias[j] = (o < 64) ? bmu[o] : blv[o - 64];
    }
    __syncthreads();

    float acc[4][8] = {};
    #pragma unroll 4
    for (int k4 = 0; k4 < 16; ++k4) {
        float4 xa[4], wb[8];
        #pragma unroll
        for (int i = 0; i < 4; ++i) {
            int r = ty + 16 * i;
            xa[i] = xs[r * 16 + (k4 ^ (r & 15))];
        }
        #pragma unroll
        for (int j = 0; j < 8; ++j) {
            int r = tx + 16 * j;
            wb[j] = ws[r * 16 + (k4 ^ (r & 15))];
        }
        #pragma unroll
        for (int i = 0; i < 4; ++i)
            #pragma unroll
            for (int j = 0; j < 8; ++j)
                acc[i][j] += xa[i].x * wb[j].x + xa[i].y * wb[j].y +
                             xa[i].z * wb[j].z + xa[i].w * wb[j].w;
    }

    #pragma unroll
    for (int i = 0; i < 4; ++i) {
        int node = nodeBase + ty + 16 * i;
        if (node < n) {
            #pragma unroll
            for (int j = 0; j < 8; ++j) {
                int o = tx + 16 * j;
                float val = acc[i][j] + bias[j];
                if (o < 64)
                    out[(size_t)node * HDIM + o] = val;
                else
                    out[(size_t)n * HDIM + (size_t)node * HDIM + (o - 64)] = val;
            }
        }
    }
}

extern "C" void kernel_launch(void* const* d_in, const int* in_sizes, int n_in,
                              void* d_out, int out_size, void* d_ws, size_t ws_size,
                              hipStream_t stream) {
    const float* x   = (const float*)d_in[0];
    const int*   ei  = (const int*)d_in[1];
    const float* W1  = (const float*)d_in[2];
    const float* b1  = (const float*)d_in[3];
    const float* Wmu = (const float*)d_in[4];
    const float* bmu = (const float*)d_in[5];
    const float* Wlv = (const float*)d_in[6];
    const float* blv = (const float*)d_in[7];
    float* out = (float*)d_out;

    const int N = in_sizes[0] / DIN;   // 100000
    const int E = in_sizes[1] / 2;     // 1000000
    const int* src = ei;
    const int* dst = ei + E;

    auto align256 = [](size_t b) { return (b + 255) & ~(size_t)255; };
    char* ws = (char*)d_ws;
    size_t off = 0;
    int* cursor = (int*)(ws + off); off += align256((size_t)N * 4);
    int* govf   = (int*)(ws + off); off += 256;
    int* slab   = (int*)(ws + off); off += align256((size_t)N * SLAB * 4);
    int* ovf    = (int*)(ws + off); off += align256((size_t)OVF_CAP * 2 * 4);
    unsigned short* hs_bf = (unsigned short*)(ws + off);
    off += align256((size_t)N * HDIM * 2);
    float* h = (float*)(ws + off); off += align256((size_t)N * HDIM * 4);

    // zero cursor + govf in one shot (adjacent)
    hipMemsetAsync(cursor, 0, align256((size_t)N * 4) + 256, stream);

    k_scatter<<<(E + 255) / 256, 256, 0, stream>>>(src, dst, cursor, slab, ovf, govf, E);
    k_h1<<<(N + 63) / 64, 256, 0, stream>>>(x, W1, cursor, hs_bf, N);
    k_gather<<<(N + 31) / 32, 256, 0, stream>>>(cursor, slab, hs_bf, h, N);
    k_overflow<<<8, 256, 0, stream>>>(govf, ovf, hs_bf, h);
    k_out<<<(N + 63) / 64, 256, 0, stream>>>(h, cursor, b1, Wmu, bmu, Wlv, blv, out, N);
}

// Round 8
// 179.524 us; speedup vs baseline: 2.7225x; 1.0823x over previous
//
#include <hip/hip_runtime.h>

#define DIN 128
#define HDIM 64
#define SLAB 32
#define OVF_CAP 65536
#define EPT 4  // edges per thread in k_scatter

__device__ __forceinline__ unsigned short f2bf(float f) {
    unsigned u = __float_as_uint(f);
    unsigned r = (u + 0x7fffu + ((u >> 16) & 1u)) >> 16;
    return (unsigned short)r;
}
__device__ __forceinline__ float lo16f(unsigned v) { return __uint_as_float(v << 16); }
__device__ __forceinline__ float hi16f(unsigned v) { return __uint_as_float(v & 0xffff0000u); }

// ---- single-pass CSR, 4 edges/thread for atomic-latency pipelining ----
__global__ __launch_bounds__(256) void k_scatter(const int* __restrict__ src,
                                                 const int* __restrict__ dst,
                                                 int* __restrict__ cursor,
                                                 int* __restrict__ slab,
                                                 int* __restrict__ ovf,
                                                 int* __restrict__ govf, int E) {
    int base = blockIdx.x * (256 * EPT) + threadIdx.x;
    int d[EPT], s[EPT], p[EPT];
    bool ok[EPT];
    #pragma unroll
    for (int q = 0; q < EPT; ++q) {
        int e = base + q * 256;
        ok[q] = e < E;
        d[q] = ok[q] ? dst[e] : 0;
        s[q] = ok[q] ? src[e] : 0;
    }
    #pragma unroll
    for (int q = 0; q < EPT; ++q)
        if (ok[q]) p[q] = atomicAdd(&cursor[d[q]], 1);
    #pragma unroll
    for (int q = 0; q < EPT; ++q) {
        if (ok[q]) {
            if (p[q] < SLAB) {
                slab[(size_t)d[q] * SLAB + p[q]] = s[q];
            } else {
                int o = atomicAdd(govf, 1);
                if (o < OVF_CAP) { ovf[2 * o] = d[q]; ovf[2 * o + 1] = s[q]; }
            }
        }
    }
}

// ---- h1 GEMM: hs[n][h] = (x[n] @ W1^T)[h] * rsqrt(deg+1), stored bf16 ----
__global__ __launch_bounds__(256) void k_h1(const float* __restrict__ x,
                                            const float* __restrict__ W1,
                                            const int* __restrict__ cursor,
                                            unsigned short* __restrict__ hs_bf, int n) {
    __shared__ float4 xs[64 * 32];
    __shared__ float4 ws[64 * 32];
    int t = threadIdx.x;
    int ty = t >> 4;
    int tx = t & 15;
    int nodeBase = blockIdx.x * 64;

    const float4* W14 = (const float4*)W1;
    #pragma unroll
    for (int i = 0; i < 8; ++i) {
        int f = t + i * 256;
        int r = f >> 5, c4 = f & 31;
        ws[r * 32 + (c4 ^ (r & 7))] = W14[f];
    }
    const float4* x4 = (const float4*)(x + (size_t)nodeBase * DIN);
    int limf4 = (n - nodeBase) * (DIN / 4);
    #pragma unroll
    for (int i = 0; i < 8; ++i) {
        int f = t + i * 256;
        int r = f >> 5, c4 = f & 31;
        float4 v = make_float4(0.f, 0.f, 0.f, 0.f);
        if (f < limf4) v = x4[f];
        xs[r * 32 + (c4 ^ (r & 7))] = v;
    }
    __syncthreads();

    float acc[4][4] = {};
    #pragma unroll 8
    for (int k4 = 0; k4 < 32; ++k4) {
        float4 xa[4], wb[4];
        #pragma unroll
        for (int i = 0; i < 4; ++i) {
            int r = ty + 16 * i;
            xa[i] = xs[r * 32 + (k4 ^ (r & 7))];
        }
        #pragma unroll
        for (int j = 0; j < 4; ++j) {
            int r = tx + 16 * j;
            wb[j] = ws[r * 32 + (k4 ^ (r & 7))];
        }
        #pragma unroll
        for (int i = 0; i < 4; ++i)
            #pragma unroll
            for (int j = 0; j < 4; ++j)
                acc[i][j] += xa[i].x * wb[j].x + xa[i].y * wb[j].y +
                             xa[i].z * wb[j].z + xa[i].w * wb[j].w;
    }

    #pragma unroll
    for (int i = 0; i < 4; ++i) {
        int node = nodeBase + ty + 16 * i;
        if (node < n) {
            float dn = rsqrtf((float)cursor[node] + 1.0f);
            #pragma unroll
            for (int j = 0; j < 4; ++j)
                hs_bf[(size_t)node * HDIM + tx + 16 * j] = f2bf(acc[i][j] * dn);
        }
    }
}

// ---- gather: h[node] = hs[node] + sum_slab hs[src]  (raw, pre-activation) ----
__global__ __launch_bounds__(256) void k_gather(const int* __restrict__ cursor,
                                                const int* __restrict__ slab,
                                                const unsigned short* __restrict__ hs_bf,
                                                float* __restrict__ h, int n) {
    int tid = threadIdx.x;
    int lane = tid & 63, wave = tid >> 6;
    int grp = lane >> 4;
    int w = lane & 15;
    const int NPW = 8;
    int base = blockIdx.x * (4 * NPW) + wave * NPW;
    for (int nn = 0; nn < NPW; ++nn) {
        int node = base + nn;
        if (node >= n) break;
        int c = cursor[node];
        int cs = (c < SLAB) ? c : SLAB;
        int sv = (lane < cs) ? slab[(size_t)node * SLAB + lane] : 0;
        uint2 v0 = *(const uint2*)(hs_bf + ((size_t)node << 6) + 4 * w);
        float sw = (grp == 0) ? 1.f : 0.f;
        float a0 = sw * lo16f(v0.x), a1 = sw * hi16f(v0.x);
        float a2 = sw * lo16f(v0.y), a3 = sw * hi16f(v0.y);
        int nfull = cs >> 2;
        for (int q = 0; q < nfull; ++q) {
            int s = __shfl(sv, 4 * q + grp);
            uint2 v = *(const uint2*)(hs_bf + ((size_t)s << 6) + 4 * w);
            a0 += lo16f(v.x); a1 += hi16f(v.x);
            a2 += lo16f(v.y); a3 += hi16f(v.y);
        }
        int r = cs & 3;
        if (r) {
            int e = 4 * nfull + grp;
            float wt = (grp < r) ? 1.f : 0.f;
            int s = __shfl(sv, (e < SLAB) ? e : 0);
            uint2 v = *(const uint2*)(hs_bf + ((size_t)s << 6) + 4 * w);
            a0 += wt * lo16f(v.x); a1 += wt * hi16f(v.x);
            a2 += wt * lo16f(v.y); a3 += wt * hi16f(v.y);
        }
        a0 += __shfl_xor(a0, 16); a0 += __shfl_xor(a0, 32);
        a1 += __shfl_xor(a1, 16); a1 += __shfl_xor(a1, 32);
        a2 += __shfl_xor(a2, 16); a2 += __shfl_xor(a2, 32);
        a3 += __shfl_xor(a3, 16); a3 += __shfl_xor(a3, 32);
        if (lane < 16)
            *(float4*)(h + ((size_t)node << 6) + 4 * w) = make_float4(a0, a1, a2, a3);
    }
}

// ---- rare overflow edges (deg > SLAB): atomic add into raw h ----
__global__ __launch_bounds__(256) void k_overflow(const int* __restrict__ govf,
                                                  const int* __restrict__ ovf,
                                                  const unsigned short* __restrict__ hs_bf,
                                                  float* __restrict__ h) {
    int novf = govf[0];
    if (novf > OVF_CAP) novf = OVF_CAP;
    int wid = (blockIdx.x * 256 + threadIdx.x) >> 6;
    int lane = threadIdx.x & 63;
    int nw = (gridDim.x * 256) >> 6;
    for (int i = wid; i < novf; i += nw) {
        int d = ovf[2 * i], s = ovf[2 * i + 1];
        atomicAdd(&h[(size_t)d * HDIM + lane],
                  lo16f((unsigned)hs_bf[(size_t)s * HDIM + lane]));
    }
}

// ---- out GEMM with fused activation on load ----
__global__ __launch_bounds__(256) void k_out(const float* __restrict__ h,
                                             const int* __restrict__ cursor,
                                             const float* __restrict__ b1,
                                             const float* __restrict__ Wmu,
                                             const float* __restrict__ bmu,
                                             const float* __restrict__ Wlv,
                                             const float* __restrict__ blv,
                                             float* __restrict__ out, int n) {
    __shared__ float4 xs[64 * 16];
    __shared__ float4 ws[128 * 16];
    int t = threadIdx.x;
    int ty = t >> 4;
    int tx = t & 15;
    int nodeBase = blockIdx.x * 64;

    const float4* Wm4 = (const float4*)Wmu;
    const float4* Wl4 = (const float4*)Wlv;
    #pragma unroll
    for (int i = 0; i < 4; ++i) {
        int f = t + i * 256;
        int r = f >> 4, c4 = f & 15;
        ws[r * 16 + (c4 ^ (r & 15))] = Wm4[f];
        int r2 = r + 64;
        ws[r2 * 16 + (c4 ^ (r2 & 15))] = Wl4[f];
    }
    const float4* h4 = (const float4*)(h + (size_t)nodeBase * HDIM);
    int limf4 = (n - nodeBase) * (HDIM / 4);
    #pragma unroll
    for (int i = 0; i < 4; ++i) {
        int f = t + i * 256;
        int r = f >> 4, c4 = f & 15;
        float4 v = make_float4(0.f, 0.f, 0.f, 0.f);
        if (f < limf4) {
            v = h4[f];
            float dn = rsqrtf((float)cursor[nodeBase + r] + 1.0f);
            float4 bb = ((const float4*)b1)[c4];
            v.x = fmaxf(fmaf(v.x, dn, bb.x), 0.f);
            v.y = fmaxf(fmaf(v.y, dn, bb.y), 0.f);
            v.z = fmaxf(fmaf(v.z, dn, bb.z), 0.f);
            v.w = fmaxf(fmaf(v.w, dn, bb.w), 0.f);
        }
        xs[r * 16 + (c4 ^ (r & 15))] = v;
    }
    float bias[8];
    #pragma unroll
    for (int j = 0; j < 8; ++j) {
        int o = tx + 16 * j;
        bias[j] = (o < 64) ? bmu[o] : blv[o - 64];
    }
    __syncthreads();

    float acc[4][8] = {};
    #pragma unroll 4
    for (int k4 = 0; k4 < 16; ++k4) {
        float4 xa[4], wb[8];
        #pragma unroll
        for (int i = 0; i < 4; ++i) {
            int r = ty + 16 * i;
            xa[i] = xs[r * 16 + (k4 ^ (r & 15))];
        }
        #pragma unroll
        for (int j = 0; j < 8; ++j) {
            int r = tx + 16 * j;
            wb[j] = ws[r * 16 + (k4 ^ (r & 15))];
        }
        #pragma unroll
        for (int i = 0; i < 4; ++i)
            #pragma unroll
            for (int j = 0; j < 8; ++j)
                acc[i][j] += xa[i].x * wb[j].x + xa[i].y * wb[j].y +
                             xa[i].z * wb[j].z + xa[i].w * wb[j].w;
    }

    #pragma unroll
    for (int i = 0; i < 4; ++i) {
        int node = nodeBase + ty + 16 * i;
        if (node < n) {
            #pragma unroll
            for (int j = 0; j < 8; ++j) {
                int o = tx + 16 * j;
                float val = acc[i][j] + bias[j];
                if (o < 64)
                    out[(size_t)node * HDIM + o] = val;
                else
                    out[(size_t)n * HDIM + (size_t)node * HDIM + (o - 64)] = val;
            }
        }
    }
}

extern "C" void kernel_launch(void* const* d_in, const int* in_sizes, int n_in,
                              void* d_out, int out_size, void* d_ws, size_t ws_size,
                              hipStream_t stream) {
    const float* x   = (const float*)d_in[0];
    const int*   ei  = (const int*)d_in[1];
    const float* W1  = (const float*)d_in[2];
    const float* b1  = (const float*)d_in[3];
    const float* Wmu = (const float*)d_in[4];
    const float* bmu = (const float*)d_in[5];
    const float* Wlv = (const float*)d_in[6];
    const float* blv = (const float*)d_in[7];
    float* out = (float*)d_out;

    const int N = in_sizes[0] / DIN;   // 100000
    const int E = in_sizes[1] / 2;     // 1000000
    const int* src = ei;
    const int* dst = ei + E;

    auto align256 = [](size_t b) { return (b + 255) & ~(size_t)255; };
    char* ws = (char*)d_ws;
    size_t off = 0;
    int* cursor = (int*)(ws + off); off += align256((size_t)N * 4);
    int* govf   = (int*)(ws + off); off += 256;
    int* slab   = (int*)(ws + off); off += align256((size_t)N * SLAB * 4);
    int* ovf    = (int*)(ws + off); off += align256((size_t)OVF_CAP * 2 * 4);
    unsigned short* hs_bf = (unsigned short*)(ws + off);
    off += align256((size_t)N * HDIM * 2);
    float* h = (float*)(ws + off); off += align256((size_t)N * HDIM * 4);

    hipMemsetAsync(cursor, 0, align256((size_t)N * 4) + 256, stream);

    k_scatter<<<(E + 256 * EPT - 1) / (256 * EPT), 256, 0, stream>>>(src, dst, cursor,
                                                                     slab, ovf, govf, E);
    k_h1<<<(N + 63) / 64, 256, 0, stream>>>(x, W1, cursor, hs_bf, N);
    k_gather<<<(N + 31) / 32, 256, 0, stream>>>(cursor, slab, hs_bf, h, N);
    k_overflow<<<8, 256, 0, stream>>>(govf, ovf, hs_bf, h);
    k_out<<<(N + 63) / 64, 256, 0, stream>>>(h, cursor, b1, Wmu, bmu, Wlv, blv, out, N);
}

// Round 9
// 167.479 us; speedup vs baseline: 2.9183x; 1.0719x over previous
//
#include <hip/hip_runtime.h>

#define DIN 128
#define HDIM 64
#define SLAB 32
#define OVF_CAP 65536
#define EPT 4  // edges per thread in scatter

__device__ __forceinline__ unsigned short f2bf(float f) {
    unsigned u = __float_as_uint(f);
    unsigned r = (u + 0x7fffu + ((u >> 16) & 1u)) >> 16;
    return (unsigned short)r;
}
__device__ __forceinline__ float lo16f(unsigned v) { return __uint_as_float(v << 16); }
__device__ __forceinline__ float hi16f(unsigned v) { return __uint_as_float(v & 0xffff0000u); }

// ---- fused: blocks [0, scatBlocks) do slab-CSR scatter; rest do h1 GEMM (raw) ----
__global__ __launch_bounds__(256) void k_scatter_h1(
        const int* __restrict__ src, const int* __restrict__ dst,
        int* __restrict__ cursor, int* __restrict__ slab,
        int* __restrict__ ovf, int* __restrict__ govf, int E,
        const float* __restrict__ x, const float* __restrict__ W1,
        unsigned short* __restrict__ hs_bf, int n, int scatBlocks) {
    __shared__ float4 xs[64 * 16];
    __shared__ float4 ws[64 * 16];
    int t = threadIdx.x;

    if ((int)blockIdx.x < scatBlocks) {
        // ---------- scatter ----------
        int base = blockIdx.x * (256 * EPT) + t;
        int d[EPT], s[EPT], p[EPT];
        bool ok[EPT];
        #pragma unroll
        for (int q = 0; q < EPT; ++q) {
            int e = base + q * 256;
            ok[q] = e < E;
            d[q] = ok[q] ? dst[e] : 0;
            s[q] = ok[q] ? src[e] : 0;
        }
        #pragma unroll
        for (int q = 0; q < EPT; ++q)
            if (ok[q]) p[q] = atomicAdd(&cursor[d[q]], 1);
        #pragma unroll
        for (int q = 0; q < EPT; ++q) {
            if (ok[q]) {
                if (p[q] < SLAB) {
                    slab[(size_t)d[q] * SLAB + p[q]] = s[q];
                } else {
                    int o = atomicAdd(govf, 1);
                    if (o < OVF_CAP) { ovf[2 * o] = d[q]; ovf[2 * o + 1] = s[q]; }
                }
            }
        }
        return;
    }

    // ---------- h1 GEMM (unscaled): hs_bf[n][h] = bf16((x[n] @ W1^T)[h]) ----------
    int bid = blockIdx.x - scatBlocks;
    int ty = t >> 4;
    int tx = t & 15;
    int nodeBase = bid * 64;
    const float4* W14 = (const float4*)W1;
    const float4* x4 = (const float4*)(x + (size_t)nodeBase * DIN);
    int limf4 = (n - nodeBase) * (DIN / 4);

    float acc[4][4] = {};
    #pragma unroll
    for (int kc = 0; kc < 2; ++kc) {
        // stage chunk kc (k4 in [kc*16, kc*16+16))
        #pragma unroll
        for (int i = 0; i < 4; ++i) {
            int e = t + i * 256;
            int r = e >> 4, c4 = e & 15;
            ws[r * 16 + (c4 ^ (r & 15))] = W14[r * 32 + kc * 16 + c4];
            int f4 = r * 32 + kc * 16 + c4;
            float4 v = make_float4(0.f, 0.f, 0.f, 0.f);
            if (f4 < limf4) v = x4[f4];
            xs[r * 16 + (c4 ^ (r & 15))] = v;
        }
        __syncthreads();
        #pragma unroll 8
        for (int k4 = 0; k4 < 16; ++k4) {
            float4 xa[4], wb[4];
            #pragma unroll
            for (int i = 0; i < 4; ++i) {
                int r = ty + 16 * i;
                xa[i] = xs[r * 16 + (k4 ^ (r & 15))];
            }
            #pragma unroll
            for (int j = 0; j < 4; ++j) {
                int r = tx + 16 * j;
                wb[j] = ws[r * 16 + (k4 ^ (r & 15))];
            }
            #pragma unroll
            for (int i = 0; i < 4; ++i)
                #pragma unroll
                for (int j = 0; j < 4; ++j)
                    acc[i][j] += xa[i].x * wb[j].x + xa[i].y * wb[j].y +
                                 xa[i].z * wb[j].z + xa[i].w * wb[j].w;
        }
        __syncthreads();
    }

    #pragma unroll
    for (int i = 0; i < 4; ++i) {
        int node = nodeBase + ty + 16 * i;
        if (node < n) {
            #pragma unroll
            for (int j = 0; j < 4; ++j)
                hs_bf[(size_t)node * HDIM + tx + 16 * j] = f2bf(acc[i][j]);
        }
    }
}

// ---- scale: hs_bf[n] *= rsqrt(deg[n]+1)  (8 threads/node, uint4 each) ----
__global__ __launch_bounds__(256) void k_scale(const int* __restrict__ cursor,
                                               unsigned short* __restrict__ hs_bf, int n) {
    int t = blockIdx.x * 256 + threadIdx.x;
    int node = t >> 3;
    if (node >= n) return;
    float dn = rsqrtf((float)cursor[node] + 1.0f);
    unsigned* p = (unsigned*)(hs_bf + ((size_t)node << 6) + 8 * (t & 7));
    uint4 v = *(uint4*)p;
    uint4 o;
    o.x = (unsigned)f2bf(lo16f(v.x) * dn) | ((unsigned)f2bf(hi16f(v.x) * dn) << 16);
    o.y = (unsigned)f2bf(lo16f(v.y) * dn) | ((unsigned)f2bf(hi16f(v.y) * dn) << 16);
    o.z = (unsigned)f2bf(lo16f(v.z) * dn) | ((unsigned)f2bf(hi16f(v.z) * dn) << 16);
    o.w = (unsigned)f2bf(lo16f(v.w) * dn) | ((unsigned)f2bf(hi16f(v.w) * dn) << 16);
    *(uint4*)p = o;
}

// ---- gather: h[node] = hs[node] + sum_slab hs[src]  (raw, pre-activation) ----
// 8 edge-groups x 8 feat-lanes (uint4 = 8 bf16 = 16B each).
__global__ __launch_bounds__(256) void k_gather(const int* __restrict__ cursor,
                                                const int* __restrict__ slab,
                                                const unsigned short* __restrict__ hs_bf,
                                                float* __restrict__ h, int n) {
    int tid = threadIdx.x;
    int lane = tid & 63, wave = tid >> 6;
    int grp = lane >> 3;   // edge slot within octet
    int w8 = lane & 7;     // feature octet: feats 8*w8..8*w8+7
    const int NPW = 8;
    int base = blockIdx.x * (4 * NPW) + wave * NPW;
    for (int nn = 0; nn < NPW; ++nn) {
        int node = base + nn;
        if (node >= n) break;
        int c = cursor[node];
        int cs = (c < SLAB) ? c : SLAB;
        int sv = (lane < cs) ? slab[(size_t)node * SLAB + lane] : 0;
        uint4 v0 = *(const uint4*)(hs_bf + ((size_t)node << 6) + 8 * w8);
        float sw = (grp == 0) ? 1.f : 0.f;
        float a0 = sw * lo16f(v0.x), a1 = sw * hi16f(v0.x);
        float a2 = sw * lo16f(v0.y), a3 = sw * hi16f(v0.y);
        float a4 = sw * lo16f(v0.z), a5 = sw * hi16f(v0.z);
        float a6 = sw * lo16f(v0.w), a7 = sw * hi16f(v0.w);
        int nfull = cs >> 3;
        for (int q = 0; q < nfull; ++q) {
            int s = __shfl(sv, 8 * q + grp);
            uint4 v = *(const uint4*)(hs_bf + ((size_t)s << 6) + 8 * w8);
            a0 += lo16f(v.x); a1 += hi16f(v.x);
            a2 += lo16f(v.y); a3 += hi16f(v.y);
            a4 += lo16f(v.z); a5 += hi16f(v.z);
            a6 += lo16f(v.w); a7 += hi16f(v.w);
        }
        int r = cs & 7;
        if (r) {
            int e = 8 * nfull + grp;
            float wt = (grp < r) ? 1.f : 0.f;
            int s = __shfl(sv, (e < SLAB) ? e : 0);
            uint4 v = *(const uint4*)(hs_bf + ((size_t)s << 6) + 8 * w8);
            a0 += wt * lo16f(v.x); a1 += wt * hi16f(v.x);
            a2 += wt * lo16f(v.y); a3 += wt * hi16f(v.y);
            a4 += wt * lo16f(v.z); a5 += wt * hi16f(v.z);
            a6 += wt * lo16f(v.w); a7 += wt * hi16f(v.w);
        }
        #define RED(A) A += __shfl_xor(A, 8); A += __shfl_xor(A, 16); A += __shfl_xor(A, 32);
        RED(a0) RED(a1) RED(a2) RED(a3) RED(a4) RED(a5) RED(a6) RED(a7)
        #undef RED
        if (lane < 8) {
            float* hp = h + ((size_t)node << 6) + 8 * w8;
            *(float4*)hp = make_float4(a0, a1, a2, a3);
            *(float4*)(hp + 4) = make_float4(a4, a5, a6, a7);
        }
    }
}

// ---- rare overflow edges (deg > SLAB): atomic add into raw h ----
__global__ __launch_bounds__(256) void k_overflow(const int* __restrict__ govf,
                                                  const int* __restrict__ ovf,
                                                  const unsigned short* __restrict__ hs_bf,
                                                  float* __restrict__ h) {
    int novf = govf[0];
    if (novf > OVF_CAP) novf = OVF_CAP;
    int wid = (blockIdx.x * 256 + threadIdx.x) >> 6;
    int lane = threadIdx.x & 63;
    int nw = (gridDim.x * 256) >> 6;
    for (int i = wid; i < novf; i += nw) {
        int d = ovf[2 * i], s = ovf[2 * i + 1];
        atomicAdd(&h[(size_t)d * HDIM + lane],
                  lo16f((unsigned)hs_bf[(size_t)s * HDIM + lane]));
    }
}

// ---- out GEMM with fused activation on load ----
__global__ __launch_bounds__(256) void k_out(const float* __restrict__ h,
                                             const int* __restrict__ cursor,
                                             const float* __restrict__ b1,
                                             const float* __restrict__ Wmu,
                                             const float* __restrict__ bmu,
                                             const float* __restrict__ Wlv,
                                             const float* __restrict__ blv,
                                             float* __restrict__ out, int n) {
    __shared__ float4 xs[64 * 16];
    __shared__ float4 ws[128 * 16];
    int t = threadIdx.x;
    int ty = t >> 4;
    int tx = t & 15;
    int nodeBase = blockIdx.x * 64;

    const float4* Wm4 = (const float4*)Wmu;
    const float4* Wl4 = (const float4*)Wlv;
    #pragma unroll
    for (int i = 0; i < 4; ++i) {
        int f = t + i * 256;
        int r = f >> 4, c4 = f & 15;
        ws[r * 16 + (c4 ^ (r & 15))] = Wm4[f];
        int r2 = r + 64;
        ws[r2 * 16 + (c4 ^ (r2 & 15))] = Wl4[f];
    }
    const float4* h4 = (const float4*)(h + (size_t)nodeBase * HDIM);
    int limf4 = (n - nodeBase) * (HDIM / 4);
    #pragma unroll
    for (int i = 0; i < 4; ++i) {
        int f = t + i * 256;
        int r = f >> 4, c4 = f & 15;
        float4 v = make_float4(0.f, 0.f, 0.f, 0.f);
        if (f < limf4) {
            v = h4[f];
            float dn = rsqrtf((float)cursor[nodeBase + r] + 1.0f);
            float4 bb = ((const float4*)b1)[c4];
            v.x = fmaxf(fmaf(v.x, dn, bb.x), 0.f);
            v.y = fmaxf(fmaf(v.y, dn, bb.y), 0.f);
            v.z = fmaxf(fmaf(v.z, dn, bb.z), 0.f);
            v.w = fmaxf(fmaf(v.w, dn, bb.w), 0.f);
        }
        xs[r * 16 + (c4 ^ (r & 15))] = v;
    }
    float bias[8];
    #pragma unroll
    for (int j = 0; j < 8; ++j) {
        int o = tx + 16 * j;
        bias[j] = (o < 64) ? bmu[o] : blv[o - 64];
    }
    __syncthreads();

    float acc[4][8] = {};
    #pragma unroll 4
    for (int k4 = 0; k4 < 16; ++k4) {
        float4 xa[4], wb[8];
        #pragma unroll
        for (int i = 0; i < 4; ++i) {
            int r = ty + 16 * i;
            xa[i] = xs[r * 16 + (k4 ^ (r & 15))];
        }
        #pragma unroll
        for (int j = 0; j < 8; ++j) {
            int r = tx + 16 * j;
            wb[j] = ws[r * 16 + (k4 ^ (r & 15))];
        }
        #pragma unroll
        for (int i = 0; i < 4; ++i)
            #pragma unroll
            for (int j = 0; j < 8; ++j)
                acc[i][j] += xa[i].x * wb[j].x + xa[i].y * wb[j].y +
                             xa[i].z * wb[j].z + xa[i].w * wb[j].w;
    }

    #pragma unroll
    for (int i = 0; i < 4; ++i) {
        int node = nodeBase + ty + 16 * i;
        if (node < n) {
            #pragma unroll
            for (int j = 0; j < 8; ++j) {
                int o = tx + 16 * j;
                float val = acc[i][j] + bias[j];
                if (o < 64)
                    out[(size_t)node * HDIM + o] = val;
                else
                    out[(size_t)n * HDIM + (size_t)node * HDIM + (o - 64)] = val;
            }
        }
    }
}

extern "C" void kernel_launch(void* const* d_in, const int* in_sizes, int n_in,
                              void* d_out, int out_size, void* d_ws, size_t ws_size,
                              hipStream_t stream) {
    const float* x   = (const float*)d_in[0];
    const int*   ei  = (const int*)d_in[1];
    const float* W1  = (const float*)d_in[2];
    const float* b1  = (const float*)d_in[3];
    const float* Wmu = (const float*)d_in[4];
    const float* bmu = (const float*)d_in[5];
    const float* Wlv = (const float*)d_in[6];
    const float* blv = (const float*)d_in[7];
    float* out = (float*)d_out;

    const int N = in_sizes[0] / DIN;   // 100000
    const int E = in_sizes[1] / 2;     // 1000000
    const int* src = ei;
    const int* dst = ei + E;

    auto align256 = [](size_t b) { return (b + 255) & ~(size_t)255; };
    char* ws = (char*)d_ws;
    size_t off = 0;
    int* cursor = (int*)(ws + off); off += align256((size_t)N * 4);
    int* govf   = (int*)(ws + off); off += 256;
    int* slab   = (int*)(ws + off); off += align256((size_t)N * SLAB * 4);
    int* ovf    = (int*)(ws + off); off += align256((size_t)OVF_CAP * 2 * 4);
    unsigned short* hs_bf = (unsigned short*)(ws + off);
    off += align256((size_t)N * HDIM * 2);
    float* h = (float*)(ws + off); off += align256((size_t)N * HDIM * 4);

    hipMemsetAsync(cursor, 0, align256((size_t)N * 4) + 256, stream);

    int scatBlocks = (E + 256 * EPT - 1) / (256 * EPT);
    int h1Blocks = (N + 63) / 64;
    k_scatter_h1<<<scatBlocks + h1Blocks, 256, 0, stream>>>(
        src, dst, cursor, slab, ovf, govf, E, x, W1, hs_bf, N, scatBlocks);
    k_scale<<<(N * 8 + 255) / 256, 256, 0, stream>>>(cursor, hs_bf, N);
    k_gather<<<(N + 31) / 32, 256, 0, stream>>>(cursor, slab, hs_bf, h, N);
    k_overflow<<<8, 256, 0, stream>>>(govf, ovf, hs_bf, h);
    k_out<<<(N + 63) / 64, 256, 0, stream>>>(h, cursor, b1, Wmu, bmu, Wlv, blv, out, N);
}